// Round 8
// baseline (300.905 us; speedup 1.0000x reference)
//
#include <hip/hip_runtime.h>

// Correlation: out[b, di*9+dj, h, w] = (1/64) * sum_c x1[b,c,h,w] * x2p[b,c,h+di,w+dj]
// x2p = x2 zero-padded by 4 each side. B=8, C=64, H=W=192.
//
// v7 (3rd submit — rounds 6/7 died with "MI355X container failed twice", a
// container-level error with no pytest/compile output; round-5 timing already showed
// infra degradation (725s npz push). Kernel audited 3x for hang/fault mechanisms:
// uniform barriers, uniform gload_lds exec, all bounds verified. If this fails at
// container level again, next round rebuilds incrementally from the v5 base.)
//
//  - 3-wave blocks (192 thr). Block = (image, 32x16 tile, di-group g3); wave w handles
//    di = 3*g3 + w. 5 blocks/CU co-resident (LDS 30KB, VGPR<=128) -> barrier drains of
//    one block overlap 4 other blocks' compute. Grid 6*12*8*3 = 1728.
//  - TWp=8: acc[9][8]=72 VGPRs; per channel 4x ds_read_b128 (64B) -> 72 FMAs (was
//    48B->36). Total b128 reads drop 2.0M -> 1.33M; LDS-pipe floor ~26-35us.
//  - x2 LDS row stride 44 (12 mod 32): the 4-lane-per-row x 16-row read pattern at
//    stride 40 would hit only 16 banks (2x conflict); stride 44 balances all 32 banks
//    at exactly 8 words/bank per b128 (verified arithmetically).
//  - Kept from v5/v6: global_load_lds staging (zero staging VGPRs, no ds_writes; all
//    lanes always active, halo/dummy lanes redirect their per-lane SOURCE to a zero
//    page -- LDS dest stays wave-uniform-base + lane*16), double-buffered LDS, one
//    barrier per chunk, stage(k+1) before compute(k), x1 from global (L1 broadcast,
//    shared by 3 waves + sibling di-group blocks), XCD image swizzle (n&7 = image)
//    with consecutive same-XCD blocks = same tile (x1/x2 L2 reuse).
//  - NOT doing: source-level distance-1 prefetch (v6 proved the scheduler undoes it;
//    VGPR only went 48->52). TLP from 15 resident waves does the hiding instead.
//  - Spill canary: WRITE_SIZE must stay ~93312 KB (output only).

constexpr int MAXD = 4;
constexpr int OD   = 9;
constexpr int ND   = 81;
constexpr int TB_W = 32;   // tile width (pixels)
constexpr int TB_H = 16;   // tile height
constexpr int TWp  = 8;    // pixels per thread along w
constexpr int CK   = 4;    // channels per LDS chunk
constexpr int NW   = 3;    // waves per block = di per block
constexpr int NT   = NW * 64;          // 192
constexpr int XROWS = TB_H + NW - 1;   // 18 x2 rows per slab
constexpr int XSTR  = 44;              // padded LDS row stride (44 % 32 == 12)

constexpr int Bc = 8, Cc = 64, Hc = 192, Wc = 192;
constexpr int HW = Hc * Wc;
constexpr int NCH   = Cc / CK;               // 16 chunks
constexpr int CSTEP = CK * HW;               // float advance per chunk
constexpr int F4_PER_CH = XROWS * XSTR / 4;  // 198 f4 per channel (11 f4/row)
constexpr int SLAB_F4_REAL = CK * F4_PER_CH; // 792 real f4 per slab
constexpr int SLOTS = 5;                     // gload_lds per thread per chunk
constexpr int SLAB_F4 = SLOTS * NT;          // 960 f4 (168 tail pad, never read)
constexpr int SLAB_F  = SLAB_F4 * 4;         // 3840 floats = 15360 B per buffer

constexpr int GX = Wc / TB_W;                // 6
constexpr int GY = Hc / TB_H;                // 12
constexpr int NBLK = GX * GY * Bc * 3;       // 1728

// 16B of guaranteed zeros (device globals are zero-initialized; never written).
__device__ __align__(16) float g_zero4[4];

__device__ inline void gload_lds16(const float* g, float* l) {
    __builtin_amdgcn_global_load_lds(
        (const __attribute__((address_space(1))) void*)g,
        (__attribute__((address_space(3))) void*)l, 16, 0, 0);
}

__global__ __launch_bounds__(NT, 2) void corr_kernel(   // cap = 256/2 = 128 VGPR
    const float* __restrict__ x1, const float* __restrict__ x2,
    float* __restrict__ out)
{
    __shared__ __align__(16) float s2[2][SLAB_F];   // 2 x 15 KB

    const int tid  = threadIdx.x;
    const int lane = tid & 63;
    const int wid  = tid >> 6;        // 0..2, di = 3*g3 + wid
    const int px8  = (lane & 3) * 8;  // 0,8,16,24
    const int gh   = lane >> 2;       // 0..15

    // ---- decode swizzled block id: image = n&7 (XCD affinity); same-XCD consecutive
    //      blocks walk di-groups of one tile, then tiles (L2 reuse of x1 + x2 rows).
    const int n    = blockIdx.x;
    const int b    = n & 7;
    const int t    = n >> 3;          // 0..215
    const int g3   = t % 3;           // di group
    const int tile = t / 3;           // 0..71
    const int ty   = tile / GX;
    const int tx   = tile - ty * GX;
    const int w0   = tx * TB_W;
    const int h0   = ty * TB_H;
    const int di   = 3 * g3 + wid;

    const float* x1b = x1 + (long)b * Cc * HW;
    const float* x2b = x2 + (long)b * Cc * HW;

    // ---------------- prologue: staging slot geometry (once) ----------------
    // Slab float4 index s = wid*320 + i*64 + lane; wave w owns s in [320w, 320w+320).
    // Decode s -> (c, r, x4): c = s/198, r = (s%198)/11, x4 = (s%198)%11.
    // Real iff s<792 && x4<10 && global row/col in-bounds; else source = zero page.
    int  q[SLOTS];      // global float offsets (chunk 0)
    int  d4[SLOTS];     // LDS float offsets (= s*4)
    bool ok[SLOTS];
#pragma unroll
    for (int i = 0; i < SLOTS; ++i) {
        int s = wid * (SLOTS * 64) + i * 64 + lane;
        d4[i] = s * 4;
        int sr = (s < SLAB_F4_REAL) ? s : 0;
        int c  = sr / F4_PER_CH;                 // /198
        int rm = sr - c * F4_PER_CH;
        int r  = rm / (XSTR / 4);                // /11
        int x4 = rm - r * (XSTR / 4);
        int rg = h0 + 3 * g3 - MAXD + r;         // global x2 row
        int gc = w0 - MAXD + x4 * 4;             // global x2 col (f4-aligned)
        ok[i] = (s < SLAB_F4_REAL) && (x4 < 10) &&
                ((unsigned)rg < (unsigned)Hc) && ((unsigned)gc < (unsigned)(Wc - 3));
        q[i]  = c * HW + rg * Wc + gc;           // only dereferenced when ok
    }

    float acc[OD][TWp];
#pragma unroll
    for (int dj = 0; dj < OD; ++dj)
#pragma unroll
        for (int p = 0; p < TWp; ++p) acc[dj][p] = 0.f;

    // x1 channel-stream offset: this thread's 8 pixels (2 f4), row h0+gh.
    int poff = (h0 + gh) * Wc + (w0 + px8);
    // LDS compute-read base row: rg = (h0+3g3-4) + (gh+wid)  =>  slab row gh+wid.
    const int ldr = gh + wid;

    auto stage = [&](int k, float* buf) {
        const int cb = k * CSTEP;
        const float* z = g_zero4;
#pragma unroll
        for (int i = 0; i < SLOTS; ++i)
            gload_lds16(ok[i] ? x2b + cb + q[i] : z, buf + d4[i]);
    };

    // chunk 0 into buffer 0
    stage(0, s2[0]);
    __syncthreads();   // vmcnt(0) drain + barrier

#pragma unroll 1
    for (int k = 0; k < NCH; ++k) {
        float* bufA = s2[k & 1];
        float* bufB = s2[(k & 1) ^ 1];

        if (k + 1 < NCH) stage(k + 1, bufB);   // overlap with this chunk's FMAs

        // ---- compute: per channel 2 global f4 (x1) + 4 ds_read_b128 (x2) -> 72 FMAs
#pragma unroll
        for (int c = 0; c < CK; ++c) {
            float4 a0 = *(const float4*)(x1b + poff);
            float4 a1 = *(const float4*)(x1b + poff + 4);
            poff += HW;
            const float* wr = bufA + c * (XROWS * XSTR) + ldr * XSTR + px8;
            float4 b0 = *(const float4*)(wr);
            float4 b1 = *(const float4*)(wr + 4);
            float4 b2 = *(const float4*)(wr + 8);
            float4 b3 = *(const float4*)(wr + 12);
            float win[16] = {b0.x, b0.y, b0.z, b0.w,  b1.x, b1.y, b1.z, b1.w,
                             b2.x, b2.y, b2.z, b2.w,  b3.x, b3.y, b3.z, b3.w};
            float av[8]  = {a0.x, a0.y, a0.z, a0.w,  a1.x, a1.y, a1.z, a1.w};
#pragma unroll
            for (int dj = 0; dj < OD; ++dj)
#pragma unroll
                for (int p = 0; p < TWp; ++p)
                    acc[dj][p] = fmaf(av[p], win[p + dj], acc[dj][p]);
        }

        __syncthreads();   // drains gload_lds (vmcnt) -> bufB ready for k+1
    }

    // ---- epilogue: 9 dj x 2 float4 stores per thread (mean over C=64)
    const float scale = 1.0f / 64.0f;
    float* ob = out + (((long)b * ND + di * OD) * Hc + (h0 + gh)) * Wc + (w0 + px8);
#pragma unroll
    for (int dj = 0; dj < OD; ++dj) {
        float4 v0, v1;
        v0.x = acc[dj][0] * scale;  v0.y = acc[dj][1] * scale;
        v0.z = acc[dj][2] * scale;  v0.w = acc[dj][3] * scale;
        v1.x = acc[dj][4] * scale;  v1.y = acc[dj][5] * scale;
        v1.z = acc[dj][6] * scale;  v1.w = acc[dj][7] * scale;
        *(float4*)(ob + (long)dj * HW)     = v0;
        *(float4*)(ob + (long)dj * HW + 4) = v1;
    }
}

extern "C" void kernel_launch(void* const* d_in, const int* in_sizes, int n_in,
                              void* d_out, int out_size, void* d_ws, size_t ws_size,
                              hipStream_t stream) {
    const float* x1 = (const float*)d_in[0];
    const float* x2 = (const float*)d_in[1];
    float* out = (float*)d_out;
    corr_kernel<<<dim3(NBLK), NT, 0, stream>>>(x1, x2, out);
}